// Round 13
// baseline (390.342 us; speedup 1.0000x reference)
//
#include <hip/hip_runtime.h>
#include <hip/hip_bf16.h>

#define BB 32
#define LL 12
#define NN 1024
#define HH 128
#define HORN 12
#define G3 384

typedef unsigned short u16;
typedef unsigned int u32;
typedef unsigned long long u64;
typedef __attribute__((ext_vector_type(8))) short short8;
typedef __attribute__((ext_vector_type(4))) float f32x4;

__device__ __forceinline__ u16 to_bf16(float f) {
    return __builtin_bit_cast(u16, __float2bfloat16(f));
}
__device__ __forceinline__ float bf_to_f(u32 bits) {
    return __builtin_bit_cast(float, bits << 16);
}
__device__ __forceinline__ void gl16(const u16* g, char* l) {
    __builtin_amdgcn_global_load_lds((const __attribute__((address_space(1))) u32*)g,
                                     (__attribute__((address_space(3))) u32*)l, 16, 0, 0);
}

// ---- A fp32 [1024][1024] -> bf16 ----
__global__ void prep_abf(const float* __restrict__ A, u16* __restrict__ Abf) {
    int t = blockIdx.x * blockDim.x + threadIdx.x;
    float4 v = ((const float4*)A)[t];
    ushort4 o;
    o.x = to_bf16(v.x); o.y = to_bf16(v.y); o.z = to_bf16(v.z); o.w = to_bf16(v.w);
    ((ushort4*)Abf)[t] = o;
}

// ---- W_h [128][384] fp32 -> W_hT [384][128] bf16 ----
__global__ void prep_whT(const float* __restrict__ W_h, u16* __restrict__ whT) {
    int t = blockIdx.x * blockDim.x + threadIdx.x;
    if (t >= HH * G3) return;
    int c = t / HH, k = t % HH;
    whT[c * HH + k] = to_bf16(W_h[k * G3 + c]);
}

// ---- one GRU step; state = bf16 hT[b][hh][j] ----
// 256 thr = 4 waves (2m x 2n of 32x64 tiles). BARRIER-FREE K-loop:
// per-wave PRIVATE staging (A 2K + B 4K per buf), 3 bufs, BK=32, 32 chunks,
// per-wave vmcnt flow only. 3 barriers/step total (vs 34 in R12).
// LDS 72K -> 2 blk/CU. Buf s @ s*24576, wave region @ +w*6144 {A@0,B@2048}.
// Post-loop overlay: Ah[64][256B]@0, T[128][128B]@16384, head-W @32768 (LAST).
template <bool FIRST, bool LAST>
__global__ __launch_bounds__(256, 2) void gru_step(
    const u16* __restrict__ Abf, const u16* __restrict__ hT_old,
    u16* __restrict__ hT_new, const u16* __restrict__ whT,
    const float* __restrict__ x, const float* __restrict__ W_x,
    const float* __restrict__ b_x, const float* __restrict__ b_h,
    const float* __restrict__ W_head, const float* __restrict__ b_head,
    float* __restrict__ out, int t) {
    __shared__ __align__(16) char smem[73728];

    int bid = blockIdx.x;
    int swz = (bid & 7) * 64 + (bid >> 3);  // 64 consecutive per XCD -> 4 batches/XCD
    int b = swz >> 4;
    int i0 = (swz & 15) * 64;
    int tid = threadIdx.x;
    int w = tid >> 6, lane = tid & 63;
    int lcol = lane & 15, kgrp = lane >> 4;
    int wm = w >> 1, wn = w & 1;
    int hq = wn * 2 + wm;                    // GEMM2 hh-quarter = own staged B range

    f32x4 acc[2][4];
#pragma unroll
    for (int m = 0; m < 2; ++m)
#pragma unroll
        for (int n = 0; n < 4; ++n) acc[m][n] = (f32x4){0.f, 0.f, 0.f, 0.f};
    u64 hreg[2][4] = {{0, 0, 0, 0}, {0, 0, 0, 0}};

    if (!FIRST) {
        int lr2 = lane >> 2, lq = lane & 3;  // row-in-16, 16B-granule slot
        u32 gsw = (u32)((lq ^ (lr2 & 3)) * 8);  // inverse store-swizzle (elems)
        const u16* agl[2]; u32 al[2];
        const u16* bgl[4]; u32 bl[4];
#pragma unroll
        for (int q = 0; q < 2; ++q) {
            agl[q] = Abf + (size_t)(i0 + wm * 32 + q * 16 + lr2) * 1024 + gsw;
            al[q] = (u32)(w * 6144 + q * 1024);
        }
#pragma unroll
        for (int q = 0; q < 4; ++q) {
            bgl[q] = hT_old + (size_t)b * 131072 + (size_t)(wn * 64 + q * 16 + lr2) * 1024 + gsw;
            bl[q] = (u32)(w * 6144 + 2048 + q * 1024);
        }

        // prologue: chunks 0,1,2 -> bufs 0,1,2 (18 loads/thread in flight)
#pragma unroll
        for (int pc = 0; pc < 3; ++pc) {
            char* base = smem + pc * 24576;
            int o = pc * 32;
#pragma unroll
            for (int q = 0; q < 2; ++q) gl16(agl[q] + o, base + al[q]);
#pragma unroll
            for (int q = 0; q < 4; ++q) gl16(bgl[q] + o, base + bl[q]);
        }

        int c0 = i0 >> 5;                    // blend rows live in chunks c0, c0+1
        u32 fsw = (u32)((kgrp ^ (lcol & 3)) * 16);
        u32 sb = 0;
        for (int c = 0; c < 32; ++c) {
            if (c < 30)      asm volatile("s_waitcnt vmcnt(12)" ::: "memory");
            else if (c < 31) asm volatile("s_waitcnt vmcnt(6)" ::: "memory");
            else             asm volatile("s_waitcnt vmcnt(0)" ::: "memory");
            __builtin_amdgcn_sched_barrier(0);

            u32 wbase = sb + (u32)(w * 6144);
            short8 a0 = *(const short8*)(smem + wbase + (u32)(lcol * 64) + fsw);
            short8 a1 = *(const short8*)(smem + wbase + (u32)((16 + lcol) * 64) + fsw);
            short8 b0 = *(const short8*)(smem + wbase + 2048 + (u32)(lcol * 64) + fsw);
            short8 b1 = *(const short8*)(smem + wbase + 2048 + (u32)((16 + lcol) * 64) + fsw);
            short8 b2 = *(const short8*)(smem + wbase + 2048 + (u32)((32 + lcol) * 64) + fsw);
            short8 b3 = *(const short8*)(smem + wbase + 2048 + (u32)((48 + lcol) * 64) + fsw);
            __builtin_amdgcn_s_setprio(1);
            acc[0][0] = __builtin_amdgcn_mfma_f32_16x16x32_bf16(a0, b0, acc[0][0], 0, 0, 0);
            acc[0][1] = __builtin_amdgcn_mfma_f32_16x16x32_bf16(a0, b1, acc[0][1], 0, 0, 0);
            acc[0][2] = __builtin_amdgcn_mfma_f32_16x16x32_bf16(a0, b2, acc[0][2], 0, 0, 0);
            acc[0][3] = __builtin_amdgcn_mfma_f32_16x16x32_bf16(a0, b3, acc[0][3], 0, 0, 0);
            acc[1][0] = __builtin_amdgcn_mfma_f32_16x16x32_bf16(a1, b0, acc[1][0], 0, 0, 0);
            acc[1][1] = __builtin_amdgcn_mfma_f32_16x16x32_bf16(a1, b1, acc[1][1], 0, 0, 0);
            acc[1][2] = __builtin_amdgcn_mfma_f32_16x16x32_bf16(a1, b2, acc[1][2], 0, 0, 0);
            acc[1][3] = __builtin_amdgcn_mfma_f32_16x16x32_bf16(a1, b3, acc[1][3], 0, 0, 0);
            __builtin_amdgcn_s_setprio(0);

            if (c == c0) {  // blend snapshot, j-local 0..31 (rt 0,1) from OWN B region
#pragma unroll
                for (int sub = 0; sub < 2; ++sub) {
                    int nloc = wm * 32 + sub * 16 + lcol;
                    u32 rb = sb + (u32)(w * 6144 + 2048 + nloc * 64);
                    u32 nsw = (u32)(nloc & 3);
#pragma unroll
                    for (int rt = 0; rt < 2; ++rt) {
                        u32 g = (u32)(rt * 2 + (kgrp >> 1));
                        hreg[sub][rt] = *(const u64*)(smem + rb + ((g ^ nsw) * 16) + (u32)((kgrp & 1) * 8));
                    }
                }
            }
            if (c == c0 + 1) {  // j-local 32..63 (rt 2,3)
#pragma unroll
                for (int sub = 0; sub < 2; ++sub) {
                    int nloc = wm * 32 + sub * 16 + lcol;
                    u32 rb = sb + (u32)(w * 6144 + 2048 + nloc * 64);
                    u32 nsw = (u32)(nloc & 3);
#pragma unroll
                    for (int rt = 2; rt < 4; ++rt) {
                        u32 g = (u32)((rt - 2) * 2 + (kgrp >> 1));
                        hreg[sub][rt] = *(const u64*)(smem + rb + ((g ^ nsw) * 16) + (u32)((kgrp & 1) * 8));
                    }
                }
            }

            asm volatile("s_waitcnt lgkmcnt(0)" ::: "memory");  // own reads done before overwrite
            __builtin_amdgcn_sched_barrier(0);
            if (c < 29) {  // chunk c+3 into the buffer just freed (own region only)
                int o = (c + 3) * 32;
#pragma unroll
                for (int q = 0; q < 2; ++q) gl16(agl[q] + o, smem + sb + al[q]);
#pragma unroll
                for (int q = 0; q < 4; ++q) gl16(bgl[q] + o, smem + sb + bl[q]);
            }
            sb = (sb == 49152u) ? 0u : sb + 24576u;
        }
    }
    __syncthreads();  // all waves done with stage bufs before Ah overlay

    // ---- Ah -> LDS bf16 [64][256B] @0 ----
#pragma unroll
    for (int m = 0; m < 2; ++m)
#pragma unroll
        for (int n = 0; n < 4; ++n)
#pragma unroll
            for (int ri = 0; ri < 4; ++ri) {
                int row = wm * 32 + m * 16 + kgrp * 4 + ri;
                int col = wn * 64 + n * 16 + lcol;
                *(u16*)(smem + row * 256 + (((u32)(2 * col)) ^ ((u32)(row & 7) << 4))) =
                    to_bf16(acc[m][n][ri]);
            }
    __syncthreads();

    // ---- GEMM2 + epilogue (T @16384); wave owns hh-quarter hq*32..+31 ----
    u32 swzl = (u32)((lcol & 7) << 4);
#pragma unroll
    for (int sub = 0; sub < 2; ++sub) {
        int hh = hq * 32 + sub * 16 + lcol;
        short8 bw[3][4];
#pragma unroll
        for (int g = 0; g < 3; ++g)
#pragma unroll
            for (int ks = 0; ks < 4; ++ks)
                bw[g][ks] = *(const short8*)(whT + (size_t)(g * 128 + hh) * 128 + ks * 32 + kgrp * 8);

        f32x4 acc2[4][3];
#pragma unroll
        for (int rt = 0; rt < 4; ++rt)
#pragma unroll
            for (int g = 0; g < 3; ++g) acc2[rt][g] = (f32x4){0.f, 0.f, 0.f, 0.f};

        __builtin_amdgcn_s_setprio(1);
#pragma unroll
        for (int rt = 0; rt < 4; ++rt) {
            u32 ab2 = (u32)((rt * 16 + lcol) * 256);
#pragma unroll
            for (int ks = 0; ks < 4; ++ks) {
                short8 a2 = *(const short8*)(smem + ab2 + (((u32)(ks * 64 + kgrp * 16)) ^ swzl));
                acc2[rt][0] = __builtin_amdgcn_mfma_f32_16x16x32_bf16(a2, bw[0][ks], acc2[rt][0], 0, 0, 0);
                acc2[rt][1] = __builtin_amdgcn_mfma_f32_16x16x32_bf16(a2, bw[1][ks], acc2[rt][1], 0, 0, 0);
                acc2[rt][2] = __builtin_amdgcn_mfma_f32_16x16x32_bf16(a2, bw[2][ks], acc2[rt][2], 0, 0, 0);
            }
        }
        __builtin_amdgcn_s_setprio(0);

        float bxz = b_x[hh], bxr = b_x[128 + hh], bxn = b_x[256 + hh];
        float bhz = b_h[hh], bhr = b_h[128 + hh], bhn = b_h[256 + hh];
        float wx0z = W_x[hh], wx0r = W_x[128 + hh], wx0n = W_x[256 + hh];
        float wx1z = W_x[G3 + hh], wx1r = W_x[G3 + 128 + hh], wx1n = W_x[G3 + 256 + hh];
#pragma unroll
        for (int rt = 0; rt < 4; ++rt) {
            u64 h4 = hreg[sub][rt];
#pragma unroll
            for (int ri = 0; ri < 4; ++ri) {
                int rl = rt * 16 + kgrp * 4 + ri;
                int i = i0 + rl;
                const float* xp = x + ((size_t)(b * LL + t) * NN + i) * 2;
                float x0 = xp[0], x1 = xp[1];
                float zin = acc2[rt][0][ri] + bhz + fmaf(x0, wx0z, fmaf(x1, wx1z, bxz));
                float rin = acc2[rt][1][ri] + bhr + fmaf(x0, wx0r, fmaf(x1, wx1r, bxr));
                float z = 1.f / (1.f + __expf(-zin));
                float rg = 1.f / (1.f + __expf(-rin));
                float nin = fmaf(rg, acc2[rt][2][ri] + bhn, fmaf(x0, wx0n, fmaf(x1, wx1n, bxn)));
                nin = fmaxf(nin, -40.f);
                float e = __expf(-2.f * nin);
                float n = (1.f - e) / (1.f + e);
                float hold = bf_to_f((u32)((h4 >> (16 * ri)) & 0xffffu));
                float hv = fmaf(z, hold - n, n);
                *(u16*)(smem + 16384 + hh * 128 + (((u32)(2 * rl)) ^ ((u32)(hh & 7) << 4))) = to_bf16(hv);
            }
        }
    }
    __syncthreads();

    if (!LAST) {
        // coalesced copy-out: hT_new[b][n][i0:i0+64]
#pragma unroll
        for (int c2 = 0; c2 < 4; ++c2) {
            int o = c2 * 4096 + tid * 16;
            int nr = o >> 7, cb = o & 127;
            uint4 v = *(const uint4*)(smem + 16384 + nr * 128 + (((u32)cb) ^ ((u32)(nr & 7) << 4)));
            *(uint4*)((char*)(hT_new + (size_t)b * 131072 + (size_t)nr * 1024 + i0) + cb) = v;
        }
    } else {
        // ---- fused head from the T-tile in LDS ----
        float* wl = (float*)(smem + 32768);
        float* blh = (float*)(smem + 38912);
        for (int ix = tid; ix < HH * HORN; ix += 256) wl[ix] = W_head[ix];
        if (tid < HORN) blh[tid] = b_head[tid];
        __syncthreads();
        int il = tid & 63, hg = tid >> 6;
        float a0 = blh[hg], a1 = blh[hg + 4], a2 = blh[hg + 8];
        for (int hh = 0; hh < 128; ++hh) {
            float hv = bf_to_f((u32)*(const u16*)(smem + 16384 + hh * 128 + (((u32)(2 * il)) ^ ((u32)(hh & 7) << 4))));
            a0 = fmaf(hv, wl[hh * HORN + hg], a0);
            a1 = fmaf(hv, wl[hh * HORN + hg + 4], a1);
            a2 = fmaf(hv, wl[hh * HORN + hg + 8], a2);
        }
        out[(size_t)(b * HORN + hg) * NN + i0 + il] = a0;
        out[(size_t)(b * HORN + hg + 4) * NN + i0 + il] = a1;
        out[(size_t)(b * HORN + hg + 8) * NN + i0 + il] = a2;
    }
}

extern "C" void kernel_launch(void* const* d_in, const int* in_sizes, int n_in,
                              void* d_out, int out_size, void* d_ws, size_t ws_size,
                              hipStream_t stream) {
    const float* x = (const float*)d_in[0];
    const float* A = (const float*)d_in[1];
    const float* W_x = (const float*)d_in[2];
    const float* b_x = (const float*)d_in[3];
    const float* W_h = (const float*)d_in[4];
    const float* b_h = (const float*)d_in[5];
    const float* W_head = (const float*)d_in[6];
    const float* b_head = (const float*)d_in[7];
    float* out = (float*)d_out;
    char* ws = (char*)d_ws;

    u16* hT0 = (u16*)(ws + 0);               // 8 MB bf16 hT [b][hh][j]
    u16* hT1 = (u16*)(ws + 8388608);         // 8 MB
    u16* Abf = (u16*)(ws + 16777216);        // 2 MB bf16 A
    u16* whT = (u16*)(ws + 18874368);        // 96 KB

    prep_abf<<<1024, 256, 0, stream>>>(A, Abf);
    prep_whT<<<(HH * G3 + 255) / 256, 256, 0, stream>>>(W_h, whT);

    // t = 0: h_old == 0
    gru_step<true, false><<<512, 256, 0, stream>>>(Abf, hT1, hT0, whT, x, W_x, b_x, b_h,
                                                   W_head, b_head, out, 0);
    u16* hTo = hT0; u16* hTn = hT1;
    for (int t = 1; t < LL - 1; ++t) {
        gru_step<false, false><<<512, 256, 0, stream>>>(Abf, hTo, hTn, whT, x, W_x, b_x, b_h,
                                                        W_head, b_head, out, t);
        u16* tmp = hTo; hTo = hTn; hTn = tmp;
    }
    // t = 11: head fused, no hT writeout
    gru_step<false, true><<<512, 256, 0, stream>>>(Abf, hTo, hTn, whT, x, W_x, b_x, b_h,
                                                   W_head, b_head, out, LL - 1);
}

// Round 14
// 294.428 us; speedup vs baseline: 1.3258x; 1.3258x over previous
//
#include <hip/hip_runtime.h>
#include <hip/hip_bf16.h>

#define BB 32
#define LL 12
#define NN 1024
#define HH 128
#define HORN 12
#define G3 384

typedef unsigned short u16;
typedef unsigned int u32;
typedef unsigned long long u64;
typedef __attribute__((ext_vector_type(8))) short short8;
typedef __attribute__((ext_vector_type(4))) float f32x4;

__device__ __forceinline__ u16 to_bf16(float f) {
    return __builtin_bit_cast(u16, __float2bfloat16(f));
}
__device__ __forceinline__ float bf_to_f(u32 bits) {
    return __builtin_bit_cast(float, bits << 16);
}
__device__ __forceinline__ void gl16(const u16* g, char* l) {
    __builtin_amdgcn_global_load_lds((const __attribute__((address_space(1))) u32*)g,
                                     (__attribute__((address_space(3))) u32*)l, 16, 0, 0);
}

// ---- A fp32 [1024][1024] -> bf16 ----
__global__ void prep_abf(const float* __restrict__ A, u16* __restrict__ Abf) {
    int t = blockIdx.x * blockDim.x + threadIdx.x;
    float4 v = ((const float4*)A)[t];
    ushort4 o;
    o.x = to_bf16(v.x); o.y = to_bf16(v.y); o.z = to_bf16(v.z); o.w = to_bf16(v.w);
    ((ushort4*)Abf)[t] = o;
}

// ---- W_h [128][384] fp32 -> W_hT [384][128] bf16 ----
__global__ void prep_whT(const float* __restrict__ W_h, u16* __restrict__ whT) {
    int t = blockIdx.x * blockDim.x + threadIdx.x;
    if (t >= HH * G3) return;
    int c = t / HH, k = t % HH;
    whT[c * HH + k] = to_bf16(W_h[k * G3 + c]);
}

// ---- one GRU step; state = bf16 hT[b][hh][j] ----
// 256 thr = 4 waves (2m x 2n of 32x64 tiles). Triple-buffered counted-vmcnt
// pipeline, SINGLE barrier per chunk: read buf[c%3], DMA chunk c+2 into
// buf[(c+2)%3] (freed at the barrier of chunk c). 18 barriers/step.
// LDS 72K -> 2 blk/CU. Buf s @ s*24576 {A[64][128B], B[128][128B]@+8192}.
// Post-loop overlay: Ah[64][256B]@0, T[128][128B]@16384, head-W @32768 (LAST).
template <bool FIRST, bool LAST>
__global__ __launch_bounds__(256, 2) void gru_step(
    const u16* __restrict__ Abf, const u16* __restrict__ hT_old,
    u16* __restrict__ hT_new, const u16* __restrict__ whT,
    const float* __restrict__ x, const float* __restrict__ W_x,
    const float* __restrict__ b_x, const float* __restrict__ b_h,
    const float* __restrict__ W_head, const float* __restrict__ b_head,
    float* __restrict__ out, int t) {
    __shared__ __align__(16) char smem[73728];

    int bid = blockIdx.x;
    int swz = (bid & 7) * 64 + (bid >> 3);  // 64 consecutive per XCD -> 4 batches/XCD
    int b = swz >> 4;
    int i0 = (swz & 15) * 64;
    int tid = threadIdx.x;
    int w = tid >> 6, lane = tid & 63;
    int lcol = lane & 15, kgrp = lane >> 4;
    int wm = w >> 1, wn = w & 1;
    u32 swzl = (u32)((lcol & 7) << 4);
    u32 a_b = (u32)((wm * 32 + lcol) * 128);
    u32 b_b = (u32)(8192 + (wn * 64 + lcol) * 128);

    f32x4 acc[2][4];
#pragma unroll
    for (int m = 0; m < 2; ++m)
#pragma unroll
        for (int n = 0; n < 4; ++n) acc[m][n] = (f32x4){0.f, 0.f, 0.f, 0.f};
    u64 hreg[2][4] = {{0, 0, 0, 0}, {0, 0, 0, 0}};

    if (!FIRST) {
        int lr3 = lane >> 3, lc8 = lane & 7;
        const u16* ag[2]; u32 al[2];
        const u16* bg[4]; u32 bl[4];
#pragma unroll
        for (int q = 0; q < 2; ++q) {
            int r = w * 16 + q * 8 + lr3;
            ag[q] = Abf + (size_t)(i0 + r) * 1024 + (lc8 ^ (r & 7)) * 8;
            al[q] = (u32)(w * 2048 + q * 1024);
        }
#pragma unroll
        for (int q = 0; q < 4; ++q) {
            int r = w * 32 + q * 8 + lr3;
            bg[q] = hT_old + (size_t)b * 131072 + (size_t)r * 1024 + (lc8 ^ (r & 7)) * 8;
            bl[q] = (u32)(8192 + w * 4096 + q * 1024);
        }

        // prologue: chunks 0,1 -> bufs 0,1 (12 loads in flight)
#pragma unroll
        for (int pc = 0; pc < 2; ++pc) {
            int o = pc * 64;
            char* base = smem + pc * 24576;
#pragma unroll
            for (int q = 0; q < 2; ++q) gl16(ag[q] + o, base + al[q]);
#pragma unroll
            for (int q = 0; q < 4; ++q) gl16(bg[q] + o, base + bl[q]);
        }

        int cstar = i0 >> 6;
        u32 sb = 0;        // read buffer: 0,1,2 rotating
        u32 db = 49152;    // DMA target: buf (c+2)%3
        for (int c = 0; c < 16; ++c) {
            if (c < 15) asm volatile("s_waitcnt vmcnt(6)" ::: "memory");
            else        asm volatile("s_waitcnt vmcnt(0)" ::: "memory");
            __builtin_amdgcn_s_barrier();
            __builtin_amdgcn_sched_barrier(0);

            if (c < 14) {  // chunk c+2 into buf freed at this barrier (≠ sb)
                int o = (c + 2) * 64;
#pragma unroll
                for (int q = 0; q < 2; ++q) gl16(ag[q] + o, smem + db + al[q]);
#pragma unroll
                for (int q = 0; q < 4; ++q) gl16(bg[q] + o, smem + db + bl[q]);
            }

            if (c == cstar) {  // snapshot blend values (cols of this B chunk)
#pragma unroll
                for (int sub = 0; sub < 2; ++sub) {
                    int hh = w * 32 + sub * 16 + lcol;
                    u32 rb = sb + 8192u + (u32)(hh * 128);
                    u32 sw = (u32)((hh & 7) << 4);
#pragma unroll
                    for (int rt = 0; rt < 4; ++rt)
                        hreg[sub][rt] = *(const u64*)(smem + rb + (((u32)(rt * 32 + kgrp * 8)) ^ sw));
                }
            }

            __builtin_amdgcn_s_setprio(1);
#pragma unroll
            for (int ks = 0; ks < 2; ++ks) {
                u32 kb = ((u32)(ks * 64 + kgrp * 16)) ^ swzl;
                short8 a0 = *(const short8*)(smem + sb + a_b + kb);
                short8 a1 = *(const short8*)(smem + sb + a_b + 2048 + kb);
                short8 b0 = *(const short8*)(smem + sb + b_b + kb);
                short8 b1 = *(const short8*)(smem + sb + b_b + 2048 + kb);
                short8 b2 = *(const short8*)(smem + sb + b_b + 4096 + kb);
                short8 b3 = *(const short8*)(smem + sb + b_b + 6144 + kb);
                acc[0][0] = __builtin_amdgcn_mfma_f32_16x16x32_bf16(a0, b0, acc[0][0], 0, 0, 0);
                acc[0][1] = __builtin_amdgcn_mfma_f32_16x16x32_bf16(a0, b1, acc[0][1], 0, 0, 0);
                acc[0][2] = __builtin_amdgcn_mfma_f32_16x16x32_bf16(a0, b2, acc[0][2], 0, 0, 0);
                acc[0][3] = __builtin_amdgcn_mfma_f32_16x16x32_bf16(a0, b3, acc[0][3], 0, 0, 0);
                acc[1][0] = __builtin_amdgcn_mfma_f32_16x16x32_bf16(a1, b0, acc[1][0], 0, 0, 0);
                acc[1][1] = __builtin_amdgcn_mfma_f32_16x16x32_bf16(a1, b1, acc[1][1], 0, 0, 0);
                acc[1][2] = __builtin_amdgcn_mfma_f32_16x16x32_bf16(a1, b2, acc[1][2], 0, 0, 0);
                acc[1][3] = __builtin_amdgcn_mfma_f32_16x16x32_bf16(a1, b3, acc[1][3], 0, 0, 0);
            }
            __builtin_amdgcn_s_setprio(0);

            sb = (sb == 49152u) ? 0u : sb + 24576u;
            db = (db == 49152u) ? 0u : db + 24576u;
        }
        asm volatile("" ::: "memory");
        __builtin_amdgcn_s_barrier();  // all waves done with stage bufs (chunk15 = buf0)
    }

    // ---- Ah -> LDS bf16 [64][256B] @0 (stage bufs dead past final barrier) ----
#pragma unroll
    for (int m = 0; m < 2; ++m)
#pragma unroll
        for (int n = 0; n < 4; ++n)
#pragma unroll
            for (int ri = 0; ri < 4; ++ri) {
                int row = wm * 32 + m * 16 + kgrp * 4 + ri;
                int col = wn * 64 + n * 16 + lcol;
                *(u16*)(smem + row * 256 + (((u32)(2 * col)) ^ ((u32)(row & 7) << 4))) =
                    to_bf16(acc[m][n][ri]);
            }
    __syncthreads();

    // ---- GEMM2 + epilogue (T @16384) ----
#pragma unroll
    for (int sub = 0; sub < 2; ++sub) {
        int hh = w * 32 + sub * 16 + lcol;
        short8 bw[3][4];
#pragma unroll
        for (int g = 0; g < 3; ++g)
#pragma unroll
            for (int ks = 0; ks < 4; ++ks)
                bw[g][ks] = *(const short8*)(whT + (size_t)(g * 128 + hh) * 128 + ks * 32 + kgrp * 8);

        f32x4 acc2[4][3];
#pragma unroll
        for (int rt = 0; rt < 4; ++rt)
#pragma unroll
            for (int g = 0; g < 3; ++g) acc2[rt][g] = (f32x4){0.f, 0.f, 0.f, 0.f};

        __builtin_amdgcn_s_setprio(1);
#pragma unroll
        for (int rt = 0; rt < 4; ++rt) {
            u32 ab2 = (u32)((rt * 16 + lcol) * 256);
#pragma unroll
            for (int ks = 0; ks < 4; ++ks) {
                short8 a2 = *(const short8*)(smem + ab2 + (((u32)(ks * 64 + kgrp * 16)) ^ swzl));
                acc2[rt][0] = __builtin_amdgcn_mfma_f32_16x16x32_bf16(a2, bw[0][ks], acc2[rt][0], 0, 0, 0);
                acc2[rt][1] = __builtin_amdgcn_mfma_f32_16x16x32_bf16(a2, bw[1][ks], acc2[rt][1], 0, 0, 0);
                acc2[rt][2] = __builtin_amdgcn_mfma_f32_16x16x32_bf16(a2, bw[2][ks], acc2[rt][2], 0, 0, 0);
            }
        }
        __builtin_amdgcn_s_setprio(0);

        float bxz = b_x[hh], bxr = b_x[128 + hh], bxn = b_x[256 + hh];
        float bhz = b_h[hh], bhr = b_h[128 + hh], bhn = b_h[256 + hh];
        float wx0z = W_x[hh], wx0r = W_x[128 + hh], wx0n = W_x[256 + hh];
        float wx1z = W_x[G3 + hh], wx1r = W_x[G3 + 128 + hh], wx1n = W_x[G3 + 256 + hh];
#pragma unroll
        for (int rt = 0; rt < 4; ++rt) {
            u64 h4 = hreg[sub][rt];
#pragma unroll
            for (int ri = 0; ri < 4; ++ri) {
                int rl = rt * 16 + kgrp * 4 + ri;
                int i = i0 + rl;
                const float* xp = x + ((size_t)(b * LL + t) * NN + i) * 2;
                float x0 = xp[0], x1 = xp[1];
                float zin = acc2[rt][0][ri] + bhz + fmaf(x0, wx0z, fmaf(x1, wx1z, bxz));
                float rin = acc2[rt][1][ri] + bhr + fmaf(x0, wx0r, fmaf(x1, wx1r, bxr));
                float z = 1.f / (1.f + __expf(-zin));
                float rg = 1.f / (1.f + __expf(-rin));
                float nin = fmaf(rg, acc2[rt][2][ri] + bhn, fmaf(x0, wx0n, fmaf(x1, wx1n, bxn)));
                nin = fmaxf(nin, -40.f);
                float e = __expf(-2.f * nin);
                float n = (1.f - e) / (1.f + e);
                float hold = bf_to_f((u32)((h4 >> (16 * ri)) & 0xffffu));
                float hv = fmaf(z, hold - n, n);
                *(u16*)(smem + 16384 + hh * 128 + (((u32)(2 * rl)) ^ ((u32)(hh & 7) << 4))) = to_bf16(hv);
            }
        }
    }
    __syncthreads();

    if (!LAST) {
        // coalesced copy-out: hT_new[b][n][i0:i0+64]
#pragma unroll
        for (int c2 = 0; c2 < 4; ++c2) {
            int o = c2 * 4096 + tid * 16;
            int nr = o >> 7, cb = o & 127;
            uint4 v = *(const uint4*)(smem + 16384 + nr * 128 + (((u32)cb) ^ ((u32)(nr & 7) << 4)));
            *(uint4*)((char*)(hT_new + (size_t)b * 131072 + (size_t)nr * 1024 + i0) + cb) = v;
        }
    } else {
        // ---- fused head from the T-tile in LDS ----
        float* wl = (float*)(smem + 32768);
        float* blh = (float*)(smem + 38912);
        for (int ix = tid; ix < HH * HORN; ix += 256) wl[ix] = W_head[ix];
        if (tid < HORN) blh[tid] = b_head[tid];
        __syncthreads();
        int il = tid & 63, hg = tid >> 6;
        float a0 = blh[hg], a1 = blh[hg + 4], a2 = blh[hg + 8];
        for (int hh = 0; hh < 128; ++hh) {
            float hv = bf_to_f((u32)*(const u16*)(smem + 16384 + hh * 128 + (((u32)(2 * il)) ^ ((u32)(hh & 7) << 4))));
            a0 = fmaf(hv, wl[hh * HORN + hg], a0);
            a1 = fmaf(hv, wl[hh * HORN + hg + 4], a1);
            a2 = fmaf(hv, wl[hh * HORN + hg + 8], a2);
        }
        out[(size_t)(b * HORN + hg) * NN + i0 + il] = a0;
        out[(size_t)(b * HORN + hg + 4) * NN + i0 + il] = a1;
        out[(size_t)(b * HORN + hg + 8) * NN + i0 + il] = a2;
    }
}

extern "C" void kernel_launch(void* const* d_in, const int* in_sizes, int n_in,
                              void* d_out, int out_size, void* d_ws, size_t ws_size,
                              hipStream_t stream) {
    const float* x = (const float*)d_in[0];
    const float* A = (const float*)d_in[1];
    const float* W_x = (const float*)d_in[2];
    const float* b_x = (const float*)d_in[3];
    const float* W_h = (const float*)d_in[4];
    const float* b_h = (const float*)d_in[5];
    const float* W_head = (const float*)d_in[6];
    const float* b_head = (const float*)d_in[7];
    float* out = (float*)d_out;
    char* ws = (char*)d_ws;

    u16* hT0 = (u16*)(ws + 0);               // 8 MB bf16 hT [b][hh][j]
    u16* hT1 = (u16*)(ws + 8388608);         // 8 MB
    u16* Abf = (u16*)(ws + 16777216);        // 2 MB bf16 A
    u16* whT = (u16*)(ws + 18874368);        // 96 KB

    prep_abf<<<1024, 256, 0, stream>>>(A, Abf);
    prep_whT<<<(HH * G3 + 255) / 256, 256, 0, stream>>>(W_h, whT);

    // t = 0: h_old == 0
    gru_step<true, false><<<512, 256, 0, stream>>>(Abf, hT1, hT0, whT, x, W_x, b_x, b_h,
                                                   W_head, b_head, out, 0);
    u16* hTo = hT0; u16* hTn = hT1;
    for (int t = 1; t < LL - 1; ++t) {
        gru_step<false, false><<<512, 256, 0, stream>>>(Abf, hTo, hTn, whT, x, W_x, b_x, b_h,
                                                        W_head, b_head, out, t);
        u16* tmp = hTo; hTo = hTn; hTn = tmp;
    }
    // t = 11: head fused, no hT writeout
    gru_step<false, true><<<512, 256, 0, stream>>>(Abf, hTo, hTn, whT, x, W_x, b_x, b_h,
                                                   W_head, b_head, out, LL - 1);
}